// Round 6
// baseline (592.319 us; speedup 1.0000x reference)
//
#include <hip/hip_runtime.h>
#include <hip/hip_bf16.h>

#define NN 100000
#define NE 1600000
#define NB 196    // buckets of 512 nodes (node>>9)
#define BSH 9
#define SCH 4096  // edges per scatter chunk

typedef __attribute__((ext_vector_type(8))) short short8;
typedef __attribute__((ext_vector_type(4))) float f32x4;

__device__ __forceinline__ unsigned bf16r(float x) {   // RNE f32->bf16 bits
    unsigned u = __float_as_uint(x);
    return (u + 0x7fffu + ((u >> 16) & 1u)) >> 16;
}
__device__ __forceinline__ unsigned pack_bf16(float a, float b) {
    return bf16r(a) | (bf16r(b) << 16);
}
__device__ __forceinline__ void unpack2(int b, float& lo, float& hi) {
    lo = __uint_as_float(((unsigned)b) << 16);
    hi = __uint_as_float(((unsigned)b) & 0xffff0000u);
}

// ================= graph build: counting-sort CSR =================
__global__ __launch_bounds__(256) void hist_kernel(const int* __restrict__ src,
                                                   const int* __restrict__ dst,
                                                   int* __restrict__ binS,
                                                   int* __restrict__ binD, int E) {
    __shared__ int hS[NB], hD[NB];
    for (int i = threadIdx.x; i < NB; i += 256) { hS[i] = 0; hD[i] = 0; }
    __syncthreads();
    for (int e = blockIdx.x * 256 + threadIdx.x; e < E; e += gridDim.x * 256) {
        atomicAdd(&hS[src[e] >> BSH], 1);
        atomicAdd(&hD[dst[e] >> BSH], 1);
    }
    __syncthreads();
    for (int i = threadIdx.x; i < NB; i += 256) {
        if (hS[i]) atomicAdd(&binS[i], hS[i]);
        if (hD[i]) atomicAdd(&binD[i], hD[i]);
    }
}

__global__ void scan_kernel(const int* __restrict__ binS, const int* __restrict__ binD,
                            int* __restrict__ curS, int* __restrict__ offS,
                            int* __restrict__ curD, int* __restrict__ offD,
                            int* __restrict__ rowptr, int E) {
    if (threadIdx.x == 0 && blockIdx.x == 0) {
        int rs = 0, rd = 0;
        for (int i = 0; i < NB; ++i) {
            curS[i] = rs; offS[i] = rs; rs += binS[i];
            curD[i] = rd; offD[i] = rd; rd += binD[i];
        }
        offS[NB] = rs;
        offD[NB] = rd;
        rowptr[NN] = E;
    }
}

__global__ __launch_bounds__(256) void scatter_kernel(const int* __restrict__ src,
                                                      const int* __restrict__ dst,
                                                      int* __restrict__ curS,
                                                      int* __restrict__ curD,
                                                      int* __restrict__ srcB,
                                                      int* __restrict__ packB, int E) {
    __shared__ int cS[NB], cD[NB], bS[NB], bD[NB];
    int base = blockIdx.x * SCH;
    for (int i = threadIdx.x; i < NB; i += 256) { cS[i] = 0; cD[i] = 0; }
    __syncthreads();
    int s[16], d[16], rS[16], rD[16];
#pragma unroll
    for (int k = 0; k < 16; ++k) {
        int idx = base + k * 256 + threadIdx.x;
        if (idx < E) {
            s[k] = src[idx]; d[k] = dst[idx];
            rS[k] = atomicAdd(&cS[s[k] >> BSH], 1);
            rD[k] = atomicAdd(&cD[d[k] >> BSH], 1);
        } else {
            s[k] = -1;
        }
    }
    __syncthreads();
    for (int i = threadIdx.x; i < NB; i += 256) {
        if (cS[i]) bS[i] = atomicAdd(&curS[i], cS[i]);
        if (cD[i]) bD[i] = atomicAdd(&curD[i], cD[i]);
    }
    __syncthreads();
#pragma unroll
    for (int k = 0; k < 16; ++k) {
        if (s[k] >= 0) {
            srcB[bS[s[k] >> BSH] + rS[k]] = s[k];
            packB[bD[d[k] >> BSH] + rD[k]] = s[k] | ((d[k] & 511) << 20);
        }
    }
}

__global__ __launch_bounds__(256) void csr_kernel(const int* __restrict__ offD,
                                                  const int* __restrict__ packB,
                                                  int* __restrict__ rowptr,
                                                  int* __restrict__ csrCol, int n) {
    int b = blockIdx.x;
    int node0 = b << BSH;
    int nNodes = min(512, n - node0);
    if (nNodes <= 0) return;
    int beg = offD[b], end = offD[b + 1];
    __shared__ int h[512];
    __shared__ int roff[512];
    for (int i = threadIdx.x; i < 512; i += 256) h[i] = 0;
    __syncthreads();
    for (int p = beg + threadIdx.x; p < end; p += 256)
        atomicAdd(&h[(packB[p] >> 20) & 511], 1);
    __syncthreads();
    if (threadIdx.x == 0) {
        int r = beg;
        for (int i = 0; i < 512; ++i) { roff[i] = r; r += h[i]; }
    }
    __syncthreads();
    for (int i = threadIdx.x; i < nNodes; i += 256) rowptr[node0 + i] = roff[i];
    for (int i = threadIdx.x; i < 512; i += 256) h[i] = 0;
    __syncthreads();
    for (int p = beg + threadIdx.x; p < end; p += 256) {
        int pk = packB[p];
        int dl = (pk >> 20) & 511;
        int r = atomicAdd(&h[dl], 1);
        csrCol[roff[dl] + r] = pk & 0xFFFFF;
    }
}

__global__ __launch_bounds__(256) void deg_kernel(const int* __restrict__ offS,
                                                  const int* __restrict__ srcB,
                                                  float* __restrict__ dinv, int n) {
    int b = blockIdx.x;
    int node0 = b << BSH;
    int nNodes = min(512, n - node0);
    if (nNodes <= 0) return;
    int beg = offS[b], end = offS[b + 1];
    __shared__ int h[512];
    for (int i = threadIdx.x; i < 512; i += 256) h[i] = 0;
    __syncthreads();
    for (int p = beg + threadIdx.x; p < end; p += 256)
        atomicAdd(&h[srcB[p] & 511], 1);
    __syncthreads();
    for (int i = threadIdx.x; i < nNodes; i += 256) {
        int d = h[i];
        dinv[node0 + i] = d > 0 ? rsqrtf((float)d) : 0.0f;
    }
}

// ================= weight prep: Bt[j][k] over j = [W0-W2 | W1 | 2*W2] cols =================
__global__ void convw_kernel(const float* __restrict__ W0, const float* __restrict__ W1,
                             const float* __restrict__ W2, short* __restrict__ Bt0,
                             short* __restrict__ Bt1, short* __restrict__ Bt2) {
    int i = blockIdx.x * blockDim.x + threadIdx.x;
    if (i < 49152) {                       // Bt0: 384 x 128
        int j = i >> 7, k = i & 127;
        int t = j >> 7, o = j & 127;
        float v = (t == 0) ? W0[k * 128 + o] - W0[2 * 16384 + k * 128 + o]
                : (t == 1) ? W0[16384 + k * 128 + o]
                           : 2.f * W0[2 * 16384 + k * 128 + o];
        Bt0[j * 128 + k] = (short)bf16r(v);
    } else if (i < 98304) {                // Bt1: 384 x 128
        int m = i - 49152;
        int j = m >> 7, k = m & 127;
        int t = j >> 7, o = j & 127;
        float v = (t == 0) ? W1[k * 128 + o] - W1[2 * 16384 + k * 128 + o]
                : (t == 1) ? W1[16384 + k * 128 + o]
                           : 2.f * W1[2 * 16384 + k * 128 + o];
        Bt1[j * 128 + k] = (short)bf16r(v);
    } else if (i < 122880) {               // Bt2: 192 x 128
        int m = i - 98304;
        int j = m >> 7, k = m & 127;
        int t = j >> 6, o = j & 63;
        float v = (t == 0) ? W2[k * 64 + o] - W2[2 * 8192 + k * 64 + o]
                : (t == 1) ? W2[8192 + k * 64 + o]
                           : 2.f * W2[2 * 8192 + k * 64 + o];
        Bt2[j * 128 + k] = (short)bf16r(v);
    }
}

// ================= GEMM: [Y0|Y1|Y2] = A[n,128] @ Bt^T + (bias into Y0) =================
// 512 threads (8 waves), BM=128, K=128 (4 steps of BK=32), BNT = 3*C.
template <int C, int AF32>
__global__ __launch_bounds__(512) void gemm_kernel(const void* Asrc,
                                                   const short* __restrict__ Bt,
                                                   const float* __restrict__ bias,
                                                   short* out0, short* out1, short* out2,
                                                   int n) {
    constexpr int BNT = 3 * C;
    constexpr int WC = BNT / 96;       // waves along N: 4 (C=128) or 2 (C=64)
    constexpr int WR = 8 / WC;         // waves along M: 2 or 4
    constexpr int WM = 128 / WR;       // 64 or 32
    constexpr int MF = WM / 16;        // 4 or 2
    constexpr int NF = 6;              // 96/16
    constexpr int LDP = 40;
    __shared__ short As[128 * LDP];
    __shared__ short Bs[BNT * LDP];

    int tid = threadIdx.x;
    int lane = tid & 63;
    int wid = tid >> 6;
    int wy = wid / WC;
    int wx = wid % WC;
    int row0 = blockIdx.x * 128;
    int l15 = lane & 15;
    int kb = (lane >> 4) * 8;

    f32x4 acc[MF][NF];
#pragma unroll
    for (int i = 0; i < MF; ++i)
#pragma unroll
        for (int j = 0; j < NF; ++j) acc[i][j] = (f32x4){0.f, 0.f, 0.f, 0.f};

    for (int k0 = 0; k0 < 128; k0 += 32) {
        // ---- stage A (128 x 32), one short8 per thread ----
        {
            int r = tid >> 2, seg = tid & 3;
            int gr = row0 + r;
            short8 v = (short8){0, 0, 0, 0, 0, 0, 0, 0};
            if (gr < n) {
                if (AF32) {
                    const float* xp = (const float*)Asrc + (size_t)gr * 128 + k0 + seg * 8;
                    float4 f0 = *(const float4*)xp;
                    float4 f1 = *(const float4*)(xp + 4);
                    v[0] = (short)bf16r(f0.x); v[1] = (short)bf16r(f0.y);
                    v[2] = (short)bf16r(f0.z); v[3] = (short)bf16r(f0.w);
                    v[4] = (short)bf16r(f1.x); v[5] = (short)bf16r(f1.y);
                    v[6] = (short)bf16r(f1.z); v[7] = (short)bf16r(f1.w);
                } else {
                    v = *(const short8*)((const short*)Asrc + (size_t)gr * 128 + k0 + seg * 8);
                }
            }
            *(short8*)&As[r * LDP + seg * 8] = v;
        }
        // ---- stage Bt (BNT x 32) ----
        constexpr int BSLOT = BNT * 4;   // short8 slots (1536 or 768)
#pragma unroll
        for (int i = 0; i < (BSLOT + 511) / 512; ++i) {
            int slot = tid + i * 512;
            if (BSLOT % 512 == 0 || slot < BSLOT) {
                int j = slot >> 2, seg = slot & 3;
                *(short8*)&Bs[j * LDP + seg * 8] =
                    *(const short8*)(Bt + (size_t)j * 128 + k0 + seg * 8);
            }
        }
        __syncthreads();

        short8 af[MF], bfr[NF];
#pragma unroll
        for (int mf = 0; mf < MF; ++mf)
            af[mf] = *(short8*)&As[(wy * WM + mf * 16 + l15) * LDP + kb];
#pragma unroll
        for (int nf = 0; nf < NF; ++nf)
            bfr[nf] = *(short8*)&Bs[(wx * 96 + nf * 16 + l15) * LDP + kb];
#pragma unroll
        for (int mf = 0; mf < MF; ++mf)
#pragma unroll
            for (int nf = 0; nf < NF; ++nf)
                acc[mf][nf] = __builtin_amdgcn_mfma_f32_16x16x32_bf16(
                    af[mf], bfr[nf], acc[mf][nf], 0, 0, 0);
        __syncthreads();
    }

    // ---- epilogue: scatter to the 3 slabs; bias folds into Y0 (t==0) ----
#pragma unroll
    for (int nf = 0; nf < NF; ++nf) {
        int colc = wx * 96 + nf * 16 + l15;
        int t = colc / C;
        int off = colc % C;
        short* P = (t == 0) ? out0 : (t == 1) ? out1 : out2;
        float bb = (t == 0) ? bias[off] : 0.f;
#pragma unroll
        for (int mf = 0; mf < MF; ++mf) {
#pragma unroll
            for (int r = 0; r < 4; ++r) {
                int row = row0 + wy * WM + mf * 16 + (lane >> 4) * 4 + r;
                if (row >= n) continue;
                P[(size_t)row * C + off] = (short)bf16r(acc[mf][nf][r] + bb);
            }
        }
    }
}

// ================= prop: O[d] = act(Add[d] - dinv[d] * sum_e dinv[s]*G[s]) =================
// C channels; one wave per dst node; 4 gathers in flight.
template <int C, int RELU, int OUTF>
__global__ __launch_bounds__(256) void prop_kernel(const short* __restrict__ G,
                                                   const short* __restrict__ Add,
                                                   void* __restrict__ O,
                                                   const int* __restrict__ rowptr,
                                                   const int* __restrict__ csrCol,
                                                   const float* __restrict__ dinv, int n) {
    constexpr int LPE = C / 8;        // lanes per edge-row (16 or 8)
    constexpr int EPG = 64 / LPE;     // edges per load group (4 or 8)
    constexpr int STEP = 4 * EPG;     // edges per inner iter (16 or 32)
    int wid = (blockIdx.x * blockDim.x + threadIdx.x) >> 6;
    int lane = threadIdx.x & 63;
    if (wid >= n) return;
    int beg = rowptr[wid];
    int c = rowptr[wid + 1] - beg;
    int sg = lane / LPE;
    int sl = lane & (LPE - 1);
    float a0 = 0, a1 = 0, a2 = 0, a3 = 0, a4 = 0, a5 = 0, a6 = 0, a7 = 0;
    for (int b0 = 0; b0 < c; b0 += 64) {
        int cb = min(64, c - b0);
        int myc = 0; float mydv = 0.f;
        if (lane < cb) {
            myc = csrCol[beg + b0 + lane];
            mydv = dinv[myc];
        }
        for (int base = 0; base < cb; base += STEP) {
            int j0 = base + sg, j1 = j0 + EPG, j2 = j0 + 2 * EPG, j3 = j0 + 3 * EPG;
            int   s0 = __shfl(myc, j0);  float w0 = __shfl(mydv, j0);
            int   s1 = __shfl(myc, j1);  float w1 = __shfl(mydv, j1);
            int   s2 = __shfl(myc, j2);  float w2 = __shfl(mydv, j2);
            int   s3 = __shfl(myc, j3);  float w3 = __shfl(mydv, j3);
            int4 v0 = *(const int4*)(G + (size_t)s0 * C + sl * 8);
            int4 v1 = *(const int4*)(G + (size_t)s1 * C + sl * 8);
            int4 v2 = *(const int4*)(G + (size_t)s2 * C + sl * 8);
            int4 v3 = *(const int4*)(G + (size_t)s3 * C + sl * 8);
            float lo, hi;
            unpack2(v0.x, lo, hi); a0 = fmaf(w0, lo, a0); a1 = fmaf(w0, hi, a1);
            unpack2(v0.y, lo, hi); a2 = fmaf(w0, lo, a2); a3 = fmaf(w0, hi, a3);
            unpack2(v0.z, lo, hi); a4 = fmaf(w0, lo, a4); a5 = fmaf(w0, hi, a5);
            unpack2(v0.w, lo, hi); a6 = fmaf(w0, lo, a6); a7 = fmaf(w0, hi, a7);
            unpack2(v1.x, lo, hi); a0 = fmaf(w1, lo, a0); a1 = fmaf(w1, hi, a1);
            unpack2(v1.y, lo, hi); a2 = fmaf(w1, lo, a2); a3 = fmaf(w1, hi, a3);
            unpack2(v1.z, lo, hi); a4 = fmaf(w1, lo, a4); a5 = fmaf(w1, hi, a5);
            unpack2(v1.w, lo, hi); a6 = fmaf(w1, lo, a6); a7 = fmaf(w1, hi, a7);
            unpack2(v2.x, lo, hi); a0 = fmaf(w2, lo, a0); a1 = fmaf(w2, hi, a1);
            unpack2(v2.y, lo, hi); a2 = fmaf(w2, lo, a2); a3 = fmaf(w2, hi, a3);
            unpack2(v2.z, lo, hi); a4 = fmaf(w2, lo, a4); a5 = fmaf(w2, hi, a5);
            unpack2(v2.w, lo, hi); a6 = fmaf(w2, lo, a6); a7 = fmaf(w2, hi, a7);
            unpack2(v3.x, lo, hi); a0 = fmaf(w3, lo, a0); a1 = fmaf(w3, hi, a1);
            unpack2(v3.y, lo, hi); a2 = fmaf(w3, lo, a2); a3 = fmaf(w3, hi, a3);
            unpack2(v3.z, lo, hi); a4 = fmaf(w3, lo, a4); a5 = fmaf(w3, hi, a5);
            unpack2(v3.w, lo, hi); a6 = fmaf(w3, lo, a6); a7 = fmaf(w3, hi, a7);
        }
    }
#pragma unroll
    for (int off = LPE; off < 64; off <<= 1) {
        a0 += __shfl_xor(a0, off); a1 += __shfl_xor(a1, off);
        a2 += __shfl_xor(a2, off); a3 += __shfl_xor(a3, off);
        a4 += __shfl_xor(a4, off); a5 += __shfl_xor(a5, off);
        a6 += __shfl_xor(a6, off); a7 += __shfl_xor(a7, off);
    }
    if (lane < LPE) {
        float scale = -dinv[wid];
        int4 ad = *(const int4*)(Add + (size_t)wid * C + sl * 8);
        float r0, r1, r2, r3, r4, r5, r6, r7, lo, hi;
        unpack2(ad.x, lo, hi); r0 = fmaf(scale, a0, lo); r1 = fmaf(scale, a1, hi);
        unpack2(ad.y, lo, hi); r2 = fmaf(scale, a2, lo); r3 = fmaf(scale, a3, hi);
        unpack2(ad.z, lo, hi); r4 = fmaf(scale, a4, lo); r5 = fmaf(scale, a5, hi);
        unpack2(ad.w, lo, hi); r6 = fmaf(scale, a6, lo); r7 = fmaf(scale, a7, hi);
        if (RELU) {
            r0 = fmaxf(r0, 0.f); r1 = fmaxf(r1, 0.f); r2 = fmaxf(r2, 0.f);
            r3 = fmaxf(r3, 0.f); r4 = fmaxf(r4, 0.f); r5 = fmaxf(r5, 0.f);
            r6 = fmaxf(r6, 0.f); r7 = fmaxf(r7, 0.f);
        }
        if (OUTF) {
            float* op = (float*)O + (size_t)wid * C + sl * 8;
            *(float4*)op = make_float4(r0, r1, r2, r3);
            *(float4*)(op + 4) = make_float4(r4, r5, r6, r7);
        } else {
            int4 w;
            w.x = pack_bf16(r0, r1);
            w.y = pack_bf16(r2, r3);
            w.z = pack_bf16(r4, r5);
            w.w = pack_bf16(r6, r7);
            *(int4*)((short*)O + (size_t)wid * C + sl * 8) = w;
        }
    }
}

extern "C" void kernel_launch(void* const* d_in, const int* in_sizes, int n_in,
                              void* d_out, int out_size, void* d_ws, size_t ws_size,
                              hipStream_t stream) {
    const float* x  = (const float*)d_in[0];
    const int*   ei = (const int*)d_in[1];
    const float* W0 = (const float*)d_in[2];
    const float* b0 = (const float*)d_in[3];
    const float* W1 = (const float*)d_in[4];
    const float* b1 = (const float*)d_in[5];
    const float* W2 = (const float*)d_in[6];
    const float* b2 = (const float*)d_in[7];
    float* out = (float*)d_out;

    const int n = NN, E = NE;
    const int* src = ei;
    const int* dst = ei + E;

    char* ws = (char*)d_ws;
    auto alloc = [&](size_t bytes) -> void* {
        void* p = (void*)ws;
        ws += (bytes + 255) & ~(size_t)255;
        return p;
    };
    int*   binS   = (int*)alloc(NB * 4);
    int*   binD   = (int*)alloc(NB * 4);
    int*   curS   = (int*)alloc((NB + 1) * 4);
    int*   offS   = (int*)alloc((NB + 1) * 4);
    int*   curD   = (int*)alloc((NB + 1) * 4);
    int*   offD   = (int*)alloc((NB + 1) * 4);
    int*   srcB   = (int*)alloc((size_t)E * 4);
    int*   packB  = (int*)alloc((size_t)E * 4);
    int*   rowptr = (int*)alloc((size_t)(n + 1) * 4);
    int*   csrCol = (int*)alloc((size_t)E * 4);
    float* dinv   = (float*)alloc((size_t)n * 4);
    short* buf0   = (short*)alloc((size_t)n * 128 * 2);   // Y0 (+ Z64 in upper half for L3)
    short* buf1   = (short*)alloc((size_t)n * 128 * 2);   // Y1 / H
    short* buf2   = (short*)alloc((size_t)n * 128 * 2);   // Y2
    short* buf3   = (short*)alloc((size_t)n * 128 * 2);   // Z
    short* Bt0    = (short*)alloc((size_t)384 * 128 * 2);
    short* Bt1    = (short*)alloc((size_t)384 * 128 * 2);
    short* Bt2    = (short*)alloc((size_t)192 * 128 * 2);

    hipMemsetAsync(binS, 0, NB * 4, stream);
    hipMemsetAsync(binD, 0, NB * 4, stream);

    const int TPB = 256;

    hist_kernel<<<256, TPB, 0, stream>>>(src, dst, binS, binD, E);
    scan_kernel<<<1, 64, 0, stream>>>(binS, binD, curS, offS, curD, offD, rowptr, E);
    int sChunks = (E + SCH - 1) / SCH;
    scatter_kernel<<<sChunks, TPB, 0, stream>>>(src, dst, curS, curD, srcB, packB, E);
    csr_kernel<<<NB, TPB, 0, stream>>>(offD, packB, rowptr, csrCol, n);
    deg_kernel<<<NB, TPB, 0, stream>>>(offS, srcB, dinv, n);

    convw_kernel<<<(122880 + 255) / 256, 256, 0, stream>>>(W0, W1, W2, Bt0, Bt1, Bt2);

    int pBlocks = (n + 3) / 4;        // 4 waves (4 nodes) per block
    int gBlocks = (n + 127) / 128;

    // ---- layer 1: A = x (fp32) ----
    gemm_kernel<128, 1><<<gBlocks, 512, 0, stream>>>(x, Bt0, b0, buf0, buf1, buf2, n);
    prop_kernel<128, 0, 0><<<pBlocks, 256, 0, stream>>>(buf2, buf1, buf3, rowptr, csrCol, dinv, n);
    prop_kernel<128, 1, 0><<<pBlocks, 256, 0, stream>>>(buf3, buf0, buf1, rowptr, csrCol, dinv, n);
    // ---- layer 2: A = H (buf1), Y1 in-place into buf1 (same-block rows; safe) ----
    gemm_kernel<128, 0><<<gBlocks, 512, 0, stream>>>(buf1, Bt1, b1, buf0, buf1, buf2, n);
    prop_kernel<128, 0, 0><<<pBlocks, 256, 0, stream>>>(buf2, buf1, buf3, rowptr, csrCol, dinv, n);
    prop_kernel<128, 1, 0><<<pBlocks, 256, 0, stream>>>(buf3, buf0, buf1, rowptr, csrCol, dinv, n);
    // ---- layer 3: C = 64, A = H (buf1); Y0->buf0, Y1->buf3, Y2->buf2 (stride 64) ----
    gemm_kernel<64, 0><<<gBlocks, 512, 0, stream>>>(buf1, Bt2, b2, buf0, buf3, buf2, n);
    prop_kernel<64, 0, 0><<<pBlocks, 256, 0, stream>>>(buf2, buf3, buf0 + (size_t)n * 64,
                                                       rowptr, csrCol, dinv, n);
    prop_kernel<64, 0, 1><<<pBlocks, 256, 0, stream>>>(buf0 + (size_t)n * 64, buf0, out,
                                                       rowptr, csrCol, dinv, n);
}

// Round 7
// 515.994 us; speedup vs baseline: 1.1479x; 1.1479x over previous
//
#include <hip/hip_runtime.h>
#include <hip/hip_bf16.h>

#define NN 100000
#define NE 1600000
#define NB 196    // buckets of 512 nodes (node>>9)
#define BSH 9
#define SCH 4096  // edges per scatter chunk

typedef __attribute__((ext_vector_type(8))) short short8;
typedef __attribute__((ext_vector_type(4))) float f32x4;

__device__ __forceinline__ unsigned bf16r(float x) {   // RNE f32->bf16 bits
    unsigned u = __float_as_uint(x);
    return (u + 0x7fffu + ((u >> 16) & 1u)) >> 16;
}
__device__ __forceinline__ unsigned pack_bf16(float a, float b) {
    return bf16r(a) | (bf16r(b) << 16);
}
__device__ __forceinline__ void unpack2(int b, float& lo, float& hi) {
    lo = __uint_as_float(((unsigned)b) << 16);
    hi = __uint_as_float(((unsigned)b) & 0xffff0000u);
}

// ================= graph build: counting-sort CSR =================
__global__ __launch_bounds__(256) void hist_kernel(const int* __restrict__ src,
                                                   const int* __restrict__ dst,
                                                   int* __restrict__ binS,
                                                   int* __restrict__ binD, int E) {
    __shared__ int hS[NB], hD[NB];
    for (int i = threadIdx.x; i < NB; i += 256) { hS[i] = 0; hD[i] = 0; }
    __syncthreads();
    for (int e = blockIdx.x * 256 + threadIdx.x; e < E; e += gridDim.x * 256) {
        atomicAdd(&hS[src[e] >> BSH], 1);
        atomicAdd(&hD[dst[e] >> BSH], 1);
    }
    __syncthreads();
    for (int i = threadIdx.x; i < NB; i += 256) {
        if (hS[i]) atomicAdd(&binS[i], hS[i]);
        if (hD[i]) atomicAdd(&binD[i], hD[i]);
    }
}

__global__ void scan_kernel(const int* __restrict__ binS, const int* __restrict__ binD,
                            int* __restrict__ curS, int* __restrict__ offS,
                            int* __restrict__ curD, int* __restrict__ offD,
                            int* __restrict__ rowptr, int E) {
    if (threadIdx.x == 0 && blockIdx.x == 0) {
        int rs = 0, rd = 0;
        for (int i = 0; i < NB; ++i) {
            curS[i] = rs; offS[i] = rs; rs += binS[i];
            curD[i] = rd; offD[i] = rd; rd += binD[i];
        }
        offS[NB] = rs;
        offD[NB] = rd;
        rowptr[NN] = E;
    }
}

__global__ __launch_bounds__(256) void scatter_kernel(const int* __restrict__ src,
                                                      const int* __restrict__ dst,
                                                      int* __restrict__ curS,
                                                      int* __restrict__ curD,
                                                      int* __restrict__ srcB,
                                                      int* __restrict__ packB, int E) {
    __shared__ int cS[NB], cD[NB], bS[NB], bD[NB];
    int base = blockIdx.x * SCH;
    for (int i = threadIdx.x; i < NB; i += 256) { cS[i] = 0; cD[i] = 0; }
    __syncthreads();
    int s[16], d[16], rS[16], rD[16];
#pragma unroll
    for (int k = 0; k < 16; ++k) {
        int idx = base + k * 256 + threadIdx.x;
        if (idx < E) {
            s[k] = src[idx]; d[k] = dst[idx];
            rS[k] = atomicAdd(&cS[s[k] >> BSH], 1);
            rD[k] = atomicAdd(&cD[d[k] >> BSH], 1);
        } else {
            s[k] = -1;
        }
    }
    __syncthreads();
    for (int i = threadIdx.x; i < NB; i += 256) {
        if (cS[i]) bS[i] = atomicAdd(&curS[i], cS[i]);
        if (cD[i]) bD[i] = atomicAdd(&curD[i], cD[i]);
    }
    __syncthreads();
#pragma unroll
    for (int k = 0; k < 16; ++k) {
        if (s[k] >= 0) {
            srcB[bS[s[k] >> BSH] + rS[k]] = s[k];
            packB[bD[d[k] >> BSH] + rD[k]] = s[k] | ((d[k] & 511) << 20);
        }
    }
}

__global__ __launch_bounds__(256) void csr_kernel(const int* __restrict__ offD,
                                                  const int* __restrict__ packB,
                                                  int* __restrict__ rowptr,
                                                  int* __restrict__ csrCol, int n) {
    int b = blockIdx.x;
    int node0 = b << BSH;
    int nNodes = min(512, n - node0);
    if (nNodes <= 0) return;
    int beg = offD[b], end = offD[b + 1];
    __shared__ int h[512];
    __shared__ int roff[512];
    for (int i = threadIdx.x; i < 512; i += 256) h[i] = 0;
    __syncthreads();
    for (int p = beg + threadIdx.x; p < end; p += 256)
        atomicAdd(&h[(packB[p] >> 20) & 511], 1);
    __syncthreads();
    if (threadIdx.x == 0) {
        int r = beg;
        for (int i = 0; i < 512; ++i) { roff[i] = r; r += h[i]; }
    }
    __syncthreads();
    for (int i = threadIdx.x; i < nNodes; i += 256) rowptr[node0 + i] = roff[i];
    for (int i = threadIdx.x; i < 512; i += 256) h[i] = 0;
    __syncthreads();
    for (int p = beg + threadIdx.x; p < end; p += 256) {
        int pk = packB[p];
        int dl = (pk >> 20) & 511;
        int r = atomicAdd(&h[dl], 1);
        csrCol[roff[dl] + r] = pk & 0xFFFFF;
    }
}

__global__ __launch_bounds__(256) void deg_kernel(const int* __restrict__ offS,
                                                  const int* __restrict__ srcB,
                                                  float* __restrict__ dinv, int n) {
    int b = blockIdx.x;
    int node0 = b << BSH;
    int nNodes = min(512, n - node0);
    if (nNodes <= 0) return;
    int beg = offS[b], end = offS[b + 1];
    __shared__ int h[512];
    for (int i = threadIdx.x; i < 512; i += 256) h[i] = 0;
    __syncthreads();
    for (int p = beg + threadIdx.x; p < end; p += 256)
        atomicAdd(&h[srcB[p] & 511], 1);
    __syncthreads();
    for (int i = threadIdx.x; i < nNodes; i += 256) {
        int d = h[i];
        dinv[node0 + i] = d > 0 ? rsqrtf((float)d) : 0.0f;
    }
}

// ================= weight prep: Bt[j][k] over j = [W0-W2 | W1 | 2*W2] cols =================
__global__ void convw_kernel(const float* __restrict__ W0, const float* __restrict__ W1,
                             const float* __restrict__ W2, short* __restrict__ Bt0,
                             short* __restrict__ Bt1, short* __restrict__ Bt2) {
    int i = blockIdx.x * blockDim.x + threadIdx.x;
    if (i < 49152) {                       // Bt0: 384 x 128
        int j = i >> 7, k = i & 127;
        int t = j >> 7, o = j & 127;
        float v = (t == 0) ? W0[k * 128 + o] - W0[2 * 16384 + k * 128 + o]
                : (t == 1) ? W0[16384 + k * 128 + o]
                           : 2.f * W0[2 * 16384 + k * 128 + o];
        Bt0[j * 128 + k] = (short)bf16r(v);
    } else if (i < 98304) {                // Bt1: 384 x 128
        int m = i - 49152;
        int j = m >> 7, k = m & 127;
        int t = j >> 7, o = j & 127;
        float v = (t == 0) ? W1[k * 128 + o] - W1[2 * 16384 + k * 128 + o]
                : (t == 1) ? W1[16384 + k * 128 + o]
                           : 2.f * W1[2 * 16384 + k * 128 + o];
        Bt1[j * 128 + k] = (short)bf16r(v);
    } else if (i < 122880) {               // Bt2: 192 x 128
        int m = i - 98304;
        int j = m >> 7, k = m & 127;
        int t = j >> 6, o = j & 63;
        float v = (t == 0) ? W2[k * 64 + o] - W2[2 * 8192 + k * 64 + o]
                : (t == 1) ? W2[8192 + k * 64 + o]
                           : 2.f * W2[2 * 8192 + k * 64 + o];
        Bt2[j * 128 + k] = (short)bf16r(v);
    }
}

// ================= GEMM: [Y0|Y1|Y2] = A[n,128] @ Bt^T + (bias into Y0) =================
// 512 threads (8 waves), BM=128, K=128 (4 steps of BK=32), BNT = 3*C.
// Register-prefetched staging; LDS-staged coalesced epilogue (int4 row writes).
template <int C, int AF32>
__global__ __launch_bounds__(512) void gemm_kernel(const void* Asrc,
                                                   const short* __restrict__ Bt,
                                                   const float* __restrict__ bias,
                                                   short* out0, short* out1, short* out2,
                                                   int n) {
    constexpr int BNT = 3 * C;
    constexpr int WC = BNT / 96;       // waves along N: 4 (C=128) or 2 (C=64)
    constexpr int WR = 8 / WC;         // waves along M: 2 or 4
    constexpr int WM = 128 / WR;       // 64 or 32
    constexpr int MF = WM / 16;        // 4 or 2
    constexpr int NF = 6;              // 96/16
    constexpr int LDP = 40;
    constexpr int BSLOT = BNT * 4;     // short8 slots for B tile
    constexpr int BITER = (BSLOT + 511) / 512;
    __shared__ short lds[(128 + BNT) * LDP];
    short* As = lds;
    short* Bs = lds + 128 * LDP;

    int tid = threadIdx.x;
    int lane = tid & 63;
    int wid = tid >> 6;
    int wy = wid / WC;
    int wx = wid % WC;
    int row0 = blockIdx.x * 128;
    int l15 = lane & 15;
    int kb = (lane >> 4) * 8;

    int ar = tid >> 2, aseg = tid & 3;   // A staging: row, 8-elem segment
    int agr = row0 + ar;

    f32x4 acc[MF][NF];
#pragma unroll
    for (int i = 0; i < MF; ++i)
#pragma unroll
        for (int j = 0; j < NF; ++j) acc[i][j] = (f32x4){0.f, 0.f, 0.f, 0.f};

    // ---- prefetch registers ----
    float4 fa0, fa1;
    short8 va;
    short8 vb[BITER];

    auto loadA = [&](int k0) {
        if (AF32) {
            if (agr < n) {
                const float* xp = (const float*)Asrc + (size_t)agr * 128 + k0 + aseg * 8;
                fa0 = *(const float4*)xp;
                fa1 = *(const float4*)(xp + 4);
            } else {
                fa0 = make_float4(0.f, 0.f, 0.f, 0.f);
                fa1 = fa0;
            }
        } else {
            va = (agr < n) ? *(const short8*)((const short*)Asrc + (size_t)agr * 128 + k0 + aseg * 8)
                           : (short8){0, 0, 0, 0, 0, 0, 0, 0};
        }
    };
    auto loadB = [&](int k0) {
#pragma unroll
        for (int i = 0; i < BITER; ++i) {
            int slot = tid + i * 512;
            if (BSLOT % 512 == 0 || slot < BSLOT) {
                int j = slot >> 2, seg = slot & 3;
                vb[i] = *(const short8*)(Bt + (size_t)j * 128 + k0 + seg * 8);
            }
        }
    };

    loadA(0);
    loadB(0);

    for (int step = 0; step < 4; ++step) {
        // ---- ds_write staged tile ----
        {
            short8 w;
            if (AF32) {
                w[0] = (short)bf16r(fa0.x); w[1] = (short)bf16r(fa0.y);
                w[2] = (short)bf16r(fa0.z); w[3] = (short)bf16r(fa0.w);
                w[4] = (short)bf16r(fa1.x); w[5] = (short)bf16r(fa1.y);
                w[6] = (short)bf16r(fa1.z); w[7] = (short)bf16r(fa1.w);
            } else {
                w = va;
            }
            *(short8*)&As[ar * LDP + aseg * 8] = w;
        }
#pragma unroll
        for (int i = 0; i < BITER; ++i) {
            int slot = tid + i * 512;
            if (BSLOT % 512 == 0 || slot < BSLOT) {
                int j = slot >> 2, seg = slot & 3;
                *(short8*)&Bs[j * LDP + seg * 8] = vb[i];
            }
        }
        __syncthreads();
        // ---- prefetch next tile (hidden under ds_read + MFMA) ----
        if (step < 3) {
            loadA((step + 1) * 32);
            loadB((step + 1) * 32);
        }
        // ---- fragments + MFMA ----
        short8 af[MF], bfr[NF];
#pragma unroll
        for (int mf = 0; mf < MF; ++mf)
            af[mf] = *(short8*)&As[(wy * WM + mf * 16 + l15) * LDP + kb];
#pragma unroll
        for (int nf = 0; nf < NF; ++nf)
            bfr[nf] = *(short8*)&Bs[(wx * 96 + nf * 16 + l15) * LDP + kb];
#pragma unroll
        for (int mf = 0; mf < MF; ++mf)
#pragma unroll
            for (int nf = 0; nf < NF; ++nf)
                acc[mf][nf] = __builtin_amdgcn_mfma_f32_16x16x32_bf16(
                    af[mf], bfr[nf], acc[mf][nf], 0, 0, 0);
        __syncthreads();
    }

    // ---- epilogue: per-wave LDS staging -> coalesced int4 row stores ----
    float bb[NF];
#pragma unroll
    for (int nf = 0; nf < NF; ++nf) {
        int colc = wx * 96 + nf * 16 + l15;
        bb[nf] = (colc < C) ? bias[colc] : 0.f;
    }
    short* st = lds + wid * 1536;   // 16 rows x 96 cols per wave; 8*1536 fits all configs
#pragma unroll
    for (int mf = 0; mf < MF; ++mf) {
#pragma unroll
        for (int nf = 0; nf < NF; ++nf) {
#pragma unroll
            for (int r = 0; r < 4; ++r) {
                int fr = (lane >> 4) * 4 + r;
                st[fr * 96 + nf * 16 + l15] = (short)bf16r(acc[mf][nf][r] + bb[nf]);
            }
        }
        // intra-wave LDS RAW: compiler inserts lgkmcnt wait (same array)
#pragma unroll
        for (int u = 0; u < 3; ++u) {
            int unit = u * 64 + lane;       // 0..191
            int rr = unit / 12;             // local row 0..15
            int seg = unit - rr * 12;       // 16B segment (8 shorts)
            int grow = row0 + wy * WM + mf * 16 + rr;
            int colc = wx * 96 + seg * 8;
            int t = colc / C, off = colc - t * C;
            short* P = (t == 0) ? out0 : (t == 1) ? out1 : out2;
            if (grow < n)
                *(int4*)&P[(size_t)grow * C + off] = *(const int4*)&st[rr * 96 + seg * 8];
        }
    }
}

// ================= prop: O[d] = act(Add[d] - dinv[d] * sum_e dinv[s]*G[s]) =================
template <int C, int RELU, int OUTF>
__global__ __launch_bounds__(256) void prop_kernel(const short* __restrict__ G,
                                                   const short* __restrict__ Add,
                                                   void* __restrict__ O,
                                                   const int* __restrict__ rowptr,
                                                   const int* __restrict__ csrCol,
                                                   const float* __restrict__ dinv, int n) {
    constexpr int LPE = C / 8;        // lanes per edge-row (16 or 8)
    constexpr int EPG = 64 / LPE;     // edges per load group (4 or 8)
    constexpr int STEP = 4 * EPG;     // edges per inner iter (16 or 32)
    int wid = (blockIdx.x * blockDim.x + threadIdx.x) >> 6;
    int lane = threadIdx.x & 63;
    if (wid >= n) return;
    int beg = rowptr[wid];
    int c = rowptr[wid + 1] - beg;
    int sg = lane / LPE;
    int sl = lane & (LPE - 1);
    float a0 = 0, a1 = 0, a2 = 0, a3 = 0, a4 = 0, a5 = 0, a6 = 0, a7 = 0;
    for (int b0 = 0; b0 < c; b0 += 64) {
        int cb = min(64, c - b0);
        int myc = 0; float mydv = 0.f;
        if (lane < cb) {
            myc = csrCol[beg + b0 + lane];
            mydv = dinv[myc];
        }
        for (int base = 0; base < cb; base += STEP) {
            int j0 = base + sg, j1 = j0 + EPG, j2 = j0 + 2 * EPG, j3 = j0 + 3 * EPG;
            int   s0 = __shfl(myc, j0);  float w0 = __shfl(mydv, j0);
            int   s1 = __shfl(myc, j1);  float w1 = __shfl(mydv, j1);
            int   s2 = __shfl(myc, j2);  float w2 = __shfl(mydv, j2);
            int   s3 = __shfl(myc, j3);  float w3 = __shfl(mydv, j3);
            int4 v0 = *(const int4*)(G + (size_t)s0 * C + sl * 8);
            int4 v1 = *(const int4*)(G + (size_t)s1 * C + sl * 8);
            int4 v2 = *(const int4*)(G + (size_t)s2 * C + sl * 8);
            int4 v3 = *(const int4*)(G + (size_t)s3 * C + sl * 8);
            float lo, hi;
            unpack2(v0.x, lo, hi); a0 = fmaf(w0, lo, a0); a1 = fmaf(w0, hi, a1);
            unpack2(v0.y, lo, hi); a2 = fmaf(w0, lo, a2); a3 = fmaf(w0, hi, a3);
            unpack2(v0.z, lo, hi); a4 = fmaf(w0, lo, a4); a5 = fmaf(w0, hi, a5);
            unpack2(v0.w, lo, hi); a6 = fmaf(w0, lo, a6); a7 = fmaf(w0, hi, a7);
            unpack2(v1.x, lo, hi); a0 = fmaf(w1, lo, a0); a1 = fmaf(w1, hi, a1);
            unpack2(v1.y, lo, hi); a2 = fmaf(w1, lo, a2); a3 = fmaf(w1, hi, a3);
            unpack2(v1.z, lo, hi); a4 = fmaf(w1, lo, a4); a5 = fmaf(w1, hi, a5);
            unpack2(v1.w, lo, hi); a6 = fmaf(w1, lo, a6); a7 = fmaf(w1, hi, a7);
            unpack2(v2.x, lo, hi); a0 = fmaf(w2, lo, a0); a1 = fmaf(w2, hi, a1);
            unpack2(v2.y, lo, hi); a2 = fmaf(w2, lo, a2); a3 = fmaf(w2, hi, a3);
            unpack2(v2.z, lo, hi); a4 = fmaf(w2, lo, a4); a5 = fmaf(w2, hi, a5);
            unpack2(v2.w, lo, hi); a6 = fmaf(w2, lo, a6); a7 = fmaf(w2, hi, a7);
            unpack2(v3.x, lo, hi); a0 = fmaf(w3, lo, a0); a1 = fmaf(w3, hi, a1);
            unpack2(v3.y, lo, hi); a2 = fmaf(w3, lo, a2); a3 = fmaf(w3, hi, a3);
            unpack2(v3.z, lo, hi); a4 = fmaf(w3, lo, a4); a5 = fmaf(w3, hi, a5);
            unpack2(v3.w, lo, hi); a6 = fmaf(w3, lo, a6); a7 = fmaf(w3, hi, a7);
        }
    }
#pragma unroll
    for (int off = LPE; off < 64; off <<= 1) {
        a0 += __shfl_xor(a0, off); a1 += __shfl_xor(a1, off);
        a2 += __shfl_xor(a2, off); a3 += __shfl_xor(a3, off);
        a4 += __shfl_xor(a4, off); a5 += __shfl_xor(a5, off);
        a6 += __shfl_xor(a6, off); a7 += __shfl_xor(a7, off);
    }
    if (lane < LPE) {
        float scale = -dinv[wid];
        int4 ad = *(const int4*)(Add + (size_t)wid * C + sl * 8);
        float r0, r1, r2, r3, r4, r5, r6, r7, lo, hi;
        unpack2(ad.x, lo, hi); r0 = fmaf(scale, a0, lo); r1 = fmaf(scale, a1, hi);
        unpack2(ad.y, lo, hi); r2 = fmaf(scale, a2, lo); r3 = fmaf(scale, a3, hi);
        unpack2(ad.z, lo, hi); r4 = fmaf(scale, a4, lo); r5 = fmaf(scale, a5, hi);
        unpack2(ad.w, lo, hi); r6 = fmaf(scale, a6, lo); r7 = fmaf(scale, a7, hi);
        if (RELU) {
            r0 = fmaxf(r0, 0.f); r1 = fmaxf(r1, 0.f); r2 = fmaxf(r2, 0.f);
            r3 = fmaxf(r3, 0.f); r4 = fmaxf(r4, 0.f); r5 = fmaxf(r5, 0.f);
            r6 = fmaxf(r6, 0.f); r7 = fmaxf(r7, 0.f);
        }
        if (OUTF) {
            float* op = (float*)O + (size_t)wid * C + sl * 8;
            *(float4*)op = make_float4(r0, r1, r2, r3);
            *(float4*)(op + 4) = make_float4(r4, r5, r6, r7);
        } else {
            int4 w;
            w.x = pack_bf16(r0, r1);
            w.y = pack_bf16(r2, r3);
            w.z = pack_bf16(r4, r5);
            w.w = pack_bf16(r6, r7);
            *(int4*)((short*)O + (size_t)wid * C + sl * 8) = w;
        }
    }
}

extern "C" void kernel_launch(void* const* d_in, const int* in_sizes, int n_in,
                              void* d_out, int out_size, void* d_ws, size_t ws_size,
                              hipStream_t stream) {
    const float* x  = (const float*)d_in[0];
    const int*   ei = (const int*)d_in[1];
    const float* W0 = (const float*)d_in[2];
    const float* b0 = (const float*)d_in[3];
    const float* W1 = (const float*)d_in[4];
    const float* b1 = (const float*)d_in[5];
    const float* W2 = (const float*)d_in[6];
    const float* b2 = (const float*)d_in[7];
    float* out = (float*)d_out;

    const int n = NN, E = NE;
    const int* src = ei;
    const int* dst = ei + E;

    char* ws = (char*)d_ws;
    auto alloc = [&](size_t bytes) -> void* {
        void* p = (void*)ws;
        ws += (bytes + 255) & ~(size_t)255;
        return p;
    };
    int*   binS   = (int*)alloc(NB * 4);
    int*   binD   = (int*)alloc(NB * 4);
    int*   curS   = (int*)alloc((NB + 1) * 4);
    int*   offS   = (int*)alloc((NB + 1) * 4);
    int*   curD   = (int*)alloc((NB + 1) * 4);
    int*   offD   = (int*)alloc((NB + 1) * 4);
    int*   srcB   = (int*)alloc((size_t)E * 4);
    int*   packB  = (int*)alloc((size_t)E * 4);
    int*   rowptr = (int*)alloc((size_t)(n + 1) * 4);
    int*   csrCol = (int*)alloc((size_t)E * 4);
    float* dinv   = (float*)alloc((size_t)n * 4);
    short* buf0   = (short*)alloc((size_t)n * 128 * 2);
    short* buf1   = (short*)alloc((size_t)n * 128 * 2);
    short* buf2   = (short*)alloc((size_t)n * 128 * 2);
    short* buf3   = (short*)alloc((size_t)n * 128 * 2);
    short* Bt0    = (short*)alloc((size_t)384 * 128 * 2);
    short* Bt1    = (short*)alloc((size_t)384 * 128 * 2);
    short* Bt2    = (short*)alloc((size_t)192 * 128 * 2);

    hipMemsetAsync(binS, 0, NB * 4, stream);
    hipMemsetAsync(binD, 0, NB * 4, stream);

    const int TPB = 256;

    hist_kernel<<<256, TPB, 0, stream>>>(src, dst, binS, binD, E);
    scan_kernel<<<1, 64, 0, stream>>>(binS, binD, curS, offS, curD, offD, rowptr, E);
    int sChunks = (E + SCH - 1) / SCH;
    scatter_kernel<<<sChunks, TPB, 0, stream>>>(src, dst, curS, curD, srcB, packB, E);
    csr_kernel<<<NB, TPB, 0, stream>>>(offD, packB, rowptr, csrCol, n);
    deg_kernel<<<NB, TPB, 0, stream>>>(offS, srcB, dinv, n);

    convw_kernel<<<(122880 + 255) / 256, 256, 0, stream>>>(W0, W1, W2, Bt0, Bt1, Bt2);

    int pBlocks = (n + 3) / 4;        // 4 waves (4 nodes) per block
    int gBlocks = (n + 127) / 128;

    // ---- layer 1: A = x (fp32) ----
    gemm_kernel<128, 1><<<gBlocks, 512, 0, stream>>>(x, Bt0, b0, buf0, buf1, buf2, n);
    prop_kernel<128, 0, 0><<<pBlocks, 256, 0, stream>>>(buf2, buf1, buf3, rowptr, csrCol, dinv, n);
    prop_kernel<128, 1, 0><<<pBlocks, 256, 0, stream>>>(buf3, buf0, buf1, rowptr, csrCol, dinv, n);
    // ---- layer 2: A = H (buf1), Y1 in-place into buf1 (own-block rows; safe) ----
    gemm_kernel<128, 0><<<gBlocks, 512, 0, stream>>>(buf1, Bt1, b1, buf0, buf1, buf2, n);
    prop_kernel<128, 0, 0><<<pBlocks, 256, 0, stream>>>(buf2, buf1, buf3, rowptr, csrCol, dinv, n);
    prop_kernel<128, 1, 0><<<pBlocks, 256, 0, stream>>>(buf3, buf0, buf1, rowptr, csrCol, dinv, n);
    // ---- layer 3: C = 64, A = H (buf1); Y0->buf0, Y1->buf3, Y2->buf2 (stride 64) ----
    gemm_kernel<64, 0><<<gBlocks, 512, 0, stream>>>(buf1, Bt2, b2, buf0, buf3, buf2, n);
    prop_kernel<64, 0, 0><<<pBlocks, 256, 0, stream>>>(buf2, buf3, buf0 + (size_t)n * 64,
                                                       rowptr, csrCol, dinv, n);
    prop_kernel<64, 0, 1><<<pBlocks, 256, 0, stream>>>(buf0 + (size_t)n * 64, buf0, out,
                                                       rowptr, csrCol, dinv, n);
}